// Round 1
// baseline (123.199 us; speedup 1.0000x reference)
//
#include <hip/hip_runtime.h>
#include <math.h>

#define NN  62    // nodes per graph
#define BGR 512   // graphs
#define FIN 128
#define HD  64
#define NC  3

// Kernel 1: build A = D^-1/2 Wsym D^-1/2 (62x62, padded to 64) and A2 = A@A -> ws
__global__ __launch_bounds__(1024) void build_A2_kernel(const float* __restrict__ tril,
                                                        float* __restrict__ A2) {
    __shared__ float A[NN * 64];
    __shared__ float dinv[NN];
    int t = threadIdx.x;
    if (t < NN) {
        float s = 0.f;
        for (int j = 0; j < NN; ++j) {
            float w = (j <= t) ? tril[t * (t + 1) / 2 + j] : tril[j * (j + 1) / 2 + t];
            s += fabsf(w);
        }
        dinv[t] = (s > 0.f) ? (1.0f / sqrtf(s)) : 0.f;
    }
    __syncthreads();
    for (int e = t; e < NN * 64; e += 1024) {
        int i = e >> 6, j = e & 63;
        float v = 0.f;
        if (j < NN) {
            float w = (j <= i) ? tril[i * (i + 1) / 2 + j] : tril[j * (j + 1) / 2 + i];
            v = dinv[i] * w * dinv[j];
        }
        A[e] = v;
    }
    __syncthreads();
    // A2[i][j] = sum_k A[i][k]*A[k][j]; zero-padded 64x64 for safe vector reads later
    for (int e = t; e < 64 * 64; e += 1024) {
        int i = e >> 6, j = e & 63;
        float s = 0.f;
        if (i < NN) {
            for (int k = 0; k < NN; ++k) s += A[i * 64 + k] * A[k * 64 + j];
        }
        A2[e] = s;
    }
}

// Kernel 2: per-graph fused  Y = X@W1^T ; Z = A2@Y + b1 ; pooled = sum_i relu(Z) ;
//           latent out + logits + log_softmax
__global__ __launch_bounds__(256) void gcn_fused(
    const float* __restrict__ x, const float* __restrict__ A2,
    const float* __restrict__ W1, const float* __restrict__ b1,
    const float* __restrict__ W2, const float* __restrict__ b2,
    float* __restrict__ out) {
    __shared__ float Xs[NN * FIN];   // 7936 floats; later reused as Ys[62*64]
    __shared__ float Wt[FIN * HD];   // 8192 floats, Wt[f*64+h]; later reused as Pr[64*33]
    __shared__ float pooledS[HD];

    int g = blockIdx.x;
    int t = threadIdx.x;
    const float* xg = x + (size_t)g * (NN * FIN);

    // ---- stage X (coalesced float4) ----
    float4* Xs4 = (float4*)Xs;
    const float4* xg4 = (const float4*)xg;
    for (int e = t; e < NN * FIN / 4; e += 256) Xs4[e] = xg4[e];
    // ---- stage W1 transposed: Wt[f*64+h] = W1[h][f] ----
    for (int e = t; e < FIN * HD; e += 256) {
        int f = e >> 6, h = e & 63;
        Wt[e] = W1[h * FIN + f];
    }
    __syncthreads();

    // ---- P1: Y[i][h] = sum_f X[i][f] * W1[h][f]; thread tile = 2 i-rows x 8 h ----
    int hq = t & 7;        // h block: 8*hq .. 8*hq+7
    int iq = t >> 3;       // 0..31; i0 = 2*iq (iq==31 -> idle, 62 rows)
    int i0 = 2 * iq;
    const float4* Wt4 = (const float4*)Wt;
    float acc[2][8];
#pragma unroll
    for (int a = 0; a < 2; ++a)
#pragma unroll
        for (int k = 0; k < 8; ++k) acc[a][k] = 0.f;

    if (i0 < NN) {
        for (int f4 = 0; f4 < FIN / 4; ++f4) {
            float4 xv0 = Xs4[i0 * 32 + f4];
            float4 xv1 = Xs4[(i0 + 1) * 32 + f4];
            float xa[2][4] = {{xv0.x, xv0.y, xv0.z, xv0.w},
                              {xv1.x, xv1.y, xv1.z, xv1.w}};
#pragma unroll
            for (int k = 0; k < 4; ++k) {
                int f = 4 * f4 + k;
                float4 w0 = Wt4[f * 16 + 2 * hq];
                float4 w1 = Wt4[f * 16 + 2 * hq + 1];
                float wv[8] = {w0.x, w0.y, w0.z, w0.w, w1.x, w1.y, w1.z, w1.w};
#pragma unroll
                for (int a = 0; a < 2; ++a)
#pragma unroll
                    for (int h8 = 0; h8 < 8; ++h8)
                        acc[a][h8] += xa[a][k] * wv[h8];
            }
        }
    }
    __syncthreads();   // all reads of Xs done -> safe to overwrite with Ys

    // ---- write Y into the Xs region: Ys[i*64+h] ----
    float4* Ys4 = (float4*)Xs;
    if (i0 < NN) {
#pragma unroll
        for (int a = 0; a < 2; ++a) {
            float4 lo = {acc[a][0], acc[a][1], acc[a][2], acc[a][3]};
            float4 hi = {acc[a][4], acc[a][5], acc[a][6], acc[a][7]};
            Ys4[(i0 + a) * 16 + 2 * hq]     = lo;
            Ys4[(i0 + a) * 16 + 2 * hq + 1] = hi;
        }
    }
    __syncthreads();

    // ---- P2: Z = A2 @ Ys + b1 ; relu; partial pool over this thread's 2 rows ----
    float z[2][8];
#pragma unroll
    for (int k = 0; k < 8; ++k) {
        float bb = b1[8 * hq + k];
        z[0][k] = bb; z[1][k] = bb;
    }
    if (i0 < NN) {
        for (int j = 0; j < NN; ++j) {
            float a0 = A2[i0 * 64 + j];
            float a1 = A2[(i0 + 1) * 64 + j];
            float4 y0 = Ys4[j * 16 + 2 * hq];
            float4 y1 = Ys4[j * 16 + 2 * hq + 1];
            float yv[8] = {y0.x, y0.y, y0.z, y0.w, y1.x, y1.y, y1.z, y1.w};
#pragma unroll
            for (int k = 0; k < 8; ++k) {
                z[0][k] += a0 * yv[k];
                z[1][k] += a1 * yv[k];
            }
        }
    }
    // partial pooled -> Pr[h][iq], stride 33 to dodge bank conflicts (reuse Wt region)
    float* Pr = Wt;
#pragma unroll
    for (int k = 0; k < 8; ++k) {
        float p = 0.f;
        if (i0 < NN) p = fmaxf(z[0][k], 0.f) + fmaxf(z[1][k], 0.f);
        Pr[(8 * hq + k) * 33 + iq] = p;
    }
    __syncthreads();

    // ---- reduce partials over iq, write latent ----
    if (t < HD) {
        float s = 0.f;
        for (int q = 0; q < 32; ++q) s += Pr[t * 33 + q];
        out[(size_t)g * HD + t] = s;
        pooledS[t] = s;
    }
    __syncthreads();

    // ---- logits + log_softmax (3 classes; each of 3 threads does all 3, cheap) ----
    if (t < NC) {
        float lg[NC];
#pragma unroll
        for (int c = 0; c < NC; ++c) {
            float zz = b2[c];
            for (int h = 0; h < HD; ++h) zz += pooledS[h] * W2[c * HD + h];
            lg[c] = zz;
        }
        float m = fmaxf(lg[0], fmaxf(lg[1], lg[2]));
        float lse = m + logf(expf(lg[0] - m) + expf(lg[1] - m) + expf(lg[2] - m));
        out[(size_t)BGR * HD + (size_t)g * NC + t] = lg[t] - lse;
    }
}

extern "C" void kernel_launch(void* const* d_in, const int* in_sizes, int n_in,
                              void* d_out, int out_size, void* d_ws, size_t ws_size,
                              hipStream_t stream) {
    const float* x    = (const float*)d_in[0];
    const float* tril = (const float*)d_in[1];
    const float* W1   = (const float*)d_in[2];
    const float* b1   = (const float*)d_in[3];
    const float* W2   = (const float*)d_in[4];
    const float* b2   = (const float*)d_in[5];
    // d_in[6] edge_index, d_in[7] batch, d_in[8] batch_size: structure is hardcoded
    float* out = (float*)d_out;
    float* A2  = (float*)d_ws;   // 64*64 floats = 16 KB

    build_A2_kernel<<<1, 1024, 0, stream>>>(tril, A2);
    gcn_fused<<<BGR, 256, 0, stream>>>(x, A2, W1, b1, W2, b2, out);
}

// Round 3
// 106.176 us; speedup vs baseline: 1.1603x; 1.1603x over previous
//
#include <hip/hip_runtime.h>
#include <math.h>

#define NN  62
#define BGR 512
#define FIN 128
#define HD  64
#define NC  3

#define FMA4(dd, ss, vv) { (dd).x += (ss)*(vv).x; (dd).y += (ss)*(vv).y; (dd).z += (ss)*(vv).z; (dd).w += (ss)*(vv).w; }
#define RELUACC(pp, qq) { (pp).x += fmaxf((qq).x,0.f); (pp).y += fmaxf((qq).y,0.f); (pp).z += fmaxf((qq).z,0.f); (pp).w += fmaxf((qq).w,0.f); }

// ws layout: A2g = ws[0 .. 4096) floats (64x64, zero-padded), W1T = ws[4096 .. 12288) (f-major 128x64)

// prep: blocks 0-3 build A2 (16 rows each); block 4 transposes W1 -> W1T
__global__ __launch_bounds__(256) void prep_kernel(const float* __restrict__ tril,
                                                   const float* __restrict__ W1,
                                                   float* __restrict__ A2g,
                                                   float* __restrict__ W1T) {
    __shared__ float LDSU[128 * 129];   // 66 KB
    const int t = threadIdx.x;
    const int b = blockIdx.x;

    if (b == 4) {
        // W1 [64][128] -> W1T [128][64], LDS-mediated so both global sides are coalesced
        for (int e = t; e < HD * FIN; e += 256) {
            int h = e >> 7, f = e & 127;
            LDSU[h * 129 + f] = W1[e];          // coalesced read, stride-1 LDS write
        }
        __syncthreads();
        for (int e = t; e < FIN * HD; e += 256) {
            int f = e >> 6, h = e & 63;
            W1T[e] = LDSU[h * 129 + f];         // stride-129 LDS read (conflict-free), coalesced write
        }
        return;
    }

    float* trilS = LDSU;            // 1953 floats
    float* dinv  = LDSU + 1984;     // 62
    float* Ac    = LDSU + 2048;     // 64*64, zero-padded

    for (int e = t; e < NN * (NN + 1) / 2; e += 256) trilS[e] = tril[e];
    __syncthreads();
    if (t < NN) {
        float s = 0.f;
        for (int j = 0; j < NN; ++j) {
            int hi = max(t, j), lo = min(t, j);
            s += fabsf(trilS[hi * (hi + 1) / 2 + lo]);
        }
        dinv[t] = (s > 0.f) ? (1.0f / sqrtf(s)) : 0.f;
    }
    __syncthreads();
    for (int e = t; e < 64 * 64; e += 256) {
        int i = e >> 6, j = e & 63;
        float v = 0.f;
        if (i < NN && j < NN) {
            int hi = max(i, j), lo = min(i, j);
            v = dinv[i] * trilS[hi * (hi + 1) / 2 + lo] * dinv[j];
        }
        Ac[e] = v;
    }
    __syncthreads();
    // A2 rows [16b, 16b+16): thread -> one float4 output
    {
        const int il = t >> 4, j4 = t & 15;
        const int i = 16 * b + il;
        const float4* Ac4 = (const float4*)Ac;
        float4 s4 = {0.f, 0.f, 0.f, 0.f};
        for (int k = 0; k < NN; ++k) {
            float a = Ac[i * 64 + k];           // 4 distinct addrs/wave (4-way, cheap)
            float4 av = Ac4[k * 16 + j4];       // 2-way max
            FMA4(s4, a, av);
        }
        ((float4*)A2g)[i * 16 + j4] = s4;
    }
}

// gcn_fused: per-graph  Y = X@W1^T ; Z = A2@Y + b1 ; pool relu ; logits + log_softmax
__global__ __launch_bounds__(256) void gcn_fused(
    const float* __restrict__ x, const float* __restrict__ A2g,
    const float* __restrict__ W1T, const float* __restrict__ b1,
    const float* __restrict__ W2, const float* __restrict__ b2,
    float* __restrict__ out) {
    __shared__ float Xs[64 * 132];   // 33 f4/row padded; reused as Yt (16 slabs x 65 f4)
    __shared__ float WU[128 * 64];   // Wt (f-major); reused: A2s (64 rows x 17 f4) + Pr + pooledS

    const int t = threadIdx.x;
    const int g = blockIdx.x;
    const int iq = t >> 4;    // 0..15 ; thread rows = iq, iq+16, iq+32, iq+48
    const int hq = t & 15;    // 0..15 ; thread h-cols = 4hq..4hq+3

    float4* Xs4 = (float4*)Xs;
    float4* WU4 = (float4*)WU;
    const float4* xg4  = (const float4*)(x + (size_t)g * NN * FIN);
    const float4* w1t4 = (const float4*)W1T;

    // ---- stage: X (padded rows), W1T (straight copy) ----
    for (int e = t; e < 2048; e += 256) {
        int row = e >> 5, f4 = e & 31;
        float4 v = {0.f, 0.f, 0.f, 0.f};
        if (e < NN * 32) v = xg4[e];
        Xs4[row * 33 + f4] = v;                 // rows 62,63 zeroed
    }
    for (int e = t; e < 2048; e += 256) WU4[e] = w1t4[e];
    __syncthreads();

    // ---- P1: Y[i][h] = sum_f X[i][f] W[f][h]; 4x4 register tile ----
    float4 acc0 = {0,0,0,0}, acc1 = {0,0,0,0}, acc2 = {0,0,0,0}, acc3 = {0,0,0,0};
    for (int f4 = 0; f4 < 32; ++f4) {
        float4 xv0 = Xs4[(iq     ) * 33 + f4];  // 4 distinct iq/wave -> 2-way max
        float4 xv1 = Xs4[(iq + 16) * 33 + f4];
        float4 xv2 = Xs4[(iq + 32) * 33 + f4];
        float4 xv3 = Xs4[(iq + 48) * 33 + f4];
        float4 wv0 = WU4[(4 * f4 + 0) * 16 + hq];  // broadcast over iq, 2-way over hq
        float4 wv1 = WU4[(4 * f4 + 1) * 16 + hq];
        float4 wv2 = WU4[(4 * f4 + 2) * 16 + hq];
        float4 wv3 = WU4[(4 * f4 + 3) * 16 + hq];
        FMA4(acc0, xv0.x, wv0); FMA4(acc0, xv0.y, wv1); FMA4(acc0, xv0.z, wv2); FMA4(acc0, xv0.w, wv3);
        FMA4(acc1, xv1.x, wv0); FMA4(acc1, xv1.y, wv1); FMA4(acc1, xv1.z, wv2); FMA4(acc1, xv1.w, wv3);
        FMA4(acc2, xv2.x, wv0); FMA4(acc2, xv2.y, wv1); FMA4(acc2, xv2.z, wv2); FMA4(acc2, xv2.w, wv3);
        FMA4(acc3, xv3.x, wv0); FMA4(acc3, xv3.y, wv1); FMA4(acc3, xv3.z, wv2); FMA4(acc3, xv3.w, wv3);
    }
    __syncthreads();   // all Xs/Wt reads complete

    // ---- write Y h-slab-major: Yt4[hq*65 + row] (slab stride 65 f4 => conflict-free P2 reads)
    float4* Yt4 = Xs4;
    Yt4[hq * 65 + iq     ] = acc0;
    Yt4[hq * 65 + iq + 16] = acc1;
    Yt4[hq * 65 + iq + 32] = acc2;
    Yt4[hq * 65 + iq + 48] = acc3;
    // ---- stage A2 into WU region, rows padded to 17 f4
    const float4* a2g4 = (const float4*)A2g;
    for (int e = t; e < 1024; e += 256) {
        int row = e >> 4, k4 = e & 15;
        WU4[row * 17 + k4] = a2g4[e];
    }
    __syncthreads();

    // ---- P2: Z = A2 @ Y + b1; 4x4 register tile over j4 ----
    float4 b1v = ((const float4*)b1)[hq];
    float4 z0 = b1v, z1 = b1v, z2 = b1v, z3 = b1v;
    for (int j4 = 0; j4 < 16; ++j4) {
        float4 a0 = WU4[(iq     ) * 17 + j4];   // 4 distinct iq -> 2-way max
        float4 a1 = WU4[(iq + 16) * 17 + j4];
        float4 a2 = WU4[(iq + 32) * 17 + j4];
        float4 a3 = WU4[(iq + 48) * 17 + j4];
        float4 y0 = Yt4[hq * 65 + 4 * j4 + 0];  // 16 distinct hq, 4hq mod 32 -> 2-way
        float4 y1 = Yt4[hq * 65 + 4 * j4 + 1];
        float4 y2 = Yt4[hq * 65 + 4 * j4 + 2];
        float4 y3 = Yt4[hq * 65 + 4 * j4 + 3];
        FMA4(z0, a0.x, y0); FMA4(z0, a0.y, y1); FMA4(z0, a0.z, y2); FMA4(z0, a0.w, y3);
        FMA4(z1, a1.x, y0); FMA4(z1, a1.y, y1); FMA4(z1, a1.z, y2); FMA4(z1, a1.w, y3);
        FMA4(z2, a2.x, y0); FMA4(z2, a2.y, y1); FMA4(z2, a2.z, y2); FMA4(z2, a2.w, y3);
        FMA4(z3, a3.x, y0); FMA4(z3, a3.y, y1); FMA4(z3, a3.z, y2); FMA4(z3, a3.w, y3);
    }

    // ---- relu + partial pool over this thread's rows (rows 62,63 masked: z held only b1)
    float4 p = {0.f, 0.f, 0.f, 0.f};
    RELUACC(p, z0);
    RELUACC(p, z1);
    RELUACC(p, z2);
    if (iq < 14) RELUACC(p, z3);   // row iq+48 >= 62 for iq in {14,15}
    float* Pr = WU + 4352;          // 64 h x 16 iq, stride 17
    Pr[(4 * hq + 0) * 17 + iq] = p.x;
    Pr[(4 * hq + 1) * 17 + iq] = p.y;
    Pr[(4 * hq + 2) * 17 + iq] = p.z;
    Pr[(4 * hq + 3) * 17 + iq] = p.w;
    __syncthreads();

    float* pooledS = WU + 5504;
    if (t < HD) {
        float s = 0.f;
        for (int q = 0; q < 16; ++q) s += Pr[t * 17 + q];
        out[(size_t)g * HD + t] = s;
        pooledS[t] = s;
    }
    __syncthreads();

    if (t < NC) {
        float lg[NC];
#pragma unroll
        for (int c = 0; c < NC; ++c) {
            float zz = b2[c];
            for (int h = 0; h < HD; ++h) zz += pooledS[h] * W2[c * HD + h];
            lg[c] = zz;
        }
        float m = fmaxf(lg[0], fmaxf(lg[1], lg[2]));
        float lse = m + logf(expf(lg[0] - m) + expf(lg[1] - m) + expf(lg[2] - m));
        out[(size_t)BGR * HD + (size_t)g * NC + t] = lg[t] - lse;
    }
}

extern "C" void kernel_launch(void* const* d_in, const int* in_sizes, int n_in,
                              void* d_out, int out_size, void* d_ws, size_t ws_size,
                              hipStream_t stream) {
    const float* x    = (const float*)d_in[0];
    const float* tril = (const float*)d_in[1];
    const float* W1   = (const float*)d_in[2];
    const float* b1   = (const float*)d_in[3];
    const float* W2   = (const float*)d_in[4];
    const float* b2   = (const float*)d_in[5];
    float* out  = (float*)d_out;
    float* A2g  = (float*)d_ws;          // 4096 floats
    float* W1T  = (float*)d_ws + 4096;   // 8192 floats

    prep_kernel<<<5, 256, 0, stream>>>(tril, W1, A2g, W1T);
    gcn_fused<<<BGR, 256, 0, stream>>>(x, A2g, W1T, b1, W2, b2, out);
}

// Round 4
// 104.438 us; speedup vs baseline: 1.1796x; 1.0166x over previous
//
#include <hip/hip_runtime.h>
#include <math.h>

#define NN  62
#define BGR 512
#define FIN 128
#define HD  64
#define NC  3

typedef __attribute__((ext_vector_type(8))) short          bf16x8;
typedef __attribute__((ext_vector_type(4))) float          f32x4;
typedef __attribute__((ext_vector_type(4))) unsigned short us4;

static __device__ __forceinline__ unsigned short f2bf(float f) {
    union { float f; unsigned u; } v; v.f = f;
    unsigned u = v.u;
    return (unsigned short)((u + 0x7fffu + ((u >> 16) & 1u)) >> 16);   // RNE
}
static __device__ __forceinline__ float bf2f(unsigned short h) {
    union { unsigned u; float f; } v; v.u = ((unsigned)h) << 16;
    return v.f;
}

// ws layout (ushort units): A2HI@0 [64*72], A2LO@4608, WHI@9216 [64*136], WLO@17920.
// A2/W pads (cols>=64 / >=128) are never frag-read; they may hold poison.

// prep: blocks 0-3 build A^2 rows (fp32) then split to bf16 hi/lo; block 4 splits W1.
__global__ __launch_bounds__(256) void prep_kernel(const float* __restrict__ tril,
                                                   const float* __restrict__ W1,
                                                   unsigned short* __restrict__ wsu) {
    __shared__ float LDSF[1984 + 64 + 4096];   // trilS, dinv, Ac (24.6 KB)
    const int t = threadIdx.x;
    const int b = blockIdx.x;

    if (b == 4) {
        for (int e = t; e < HD * FIN; e += 256) {
            int h = e >> 7, f = e & 127;
            float w = W1[e];
            unsigned short hi = f2bf(w);
            unsigned short lo = f2bf(w - bf2f(hi));
            wsu[9216  + h * 136 + f] = hi;
            wsu[17920 + h * 136 + f] = lo;
        }
        return;
    }

    float* trilS = LDSF;
    float* dinv  = LDSF + 1984;
    float* Ac    = LDSF + 2048;

    for (int e = t; e < NN * (NN + 1) / 2; e += 256) trilS[e] = tril[e];
    __syncthreads();
    if (t < NN) {
        float s = 0.f;
        for (int j = 0; j < NN; ++j) {
            int hi = max(t, j), lo = min(t, j);
            s += fabsf(trilS[hi * (hi + 1) / 2 + lo]);
        }
        dinv[t] = (s > 0.f) ? (1.0f / sqrtf(s)) : 0.f;
    }
    __syncthreads();
    for (int e = t; e < 64 * 64; e += 256) {
        int i = e >> 6, j = e & 63;
        float v = 0.f;
        if (i < NN && j < NN) {
            int hi = max(i, j), lo = min(i, j);
            v = dinv[i] * trilS[hi * (hi + 1) / 2 + lo] * dinv[j];
        }
        Ac[e] = v;
    }
    __syncthreads();
    {
        const int il = t >> 4, j4 = t & 15;
        const int i = 16 * b + il;
        const float4* Ac4 = (const float4*)Ac;
        float4 s4 = {0.f, 0.f, 0.f, 0.f};
        for (int k = 0; k < NN; ++k) {
            float a = Ac[i * 64 + k];
            float4 av = Ac4[k * 16 + j4];
            s4.x += a * av.x; s4.y += a * av.y; s4.z += a * av.z; s4.w += a * av.w;
        }
        us4 hh, ll;
        hh[0] = f2bf(s4.x); ll[0] = f2bf(s4.x - bf2f(hh[0]));
        hh[1] = f2bf(s4.y); ll[1] = f2bf(s4.y - bf2f(hh[1]));
        hh[2] = f2bf(s4.z); ll[2] = f2bf(s4.z - bf2f(hh[2]));
        hh[3] = f2bf(s4.w); ll[3] = f2bf(s4.w - bf2f(hh[3]));
        *(us4*)&wsu[       i * 72 + 4 * j4] = hh;
        *(us4*)&wsu[4608 + i * 72 + 4 * j4] = ll;
    }
}

// gcn: per graph, MFMA split-bf16x4:  Y = X@W1^T (K=128) ; Z = A2@Y (K=64) ; relu-pool ; head.
// LDS SH (ushort): phase1 XHI@0[64*136] XLO@8704 WHI@17408 WLO@26112
//                  phase2 YTHI@0[64*72] YTLO@4608 A2HI@9216 A2LO@13824
__global__ __launch_bounds__(256) void gcn_fused(
    const float* __restrict__ x, const unsigned short* __restrict__ wsu,
    const float* __restrict__ b1, const float* __restrict__ W2,
    const float* __restrict__ b2, float* __restrict__ out) {
    __shared__ unsigned short SH[34816];          // 68 KB
    __shared__ float TAIL[64 * 17 + 64 + 64];     // partial, pooledS, b1S
    float* partial = TAIL;
    float* pooledS = TAIL + 1088;
    float* b1S     = TAIL + 1152;

    const int t = threadIdx.x;
    const int g = blockIdx.x;
    const int lane = t & 63, wv = t >> 6, quad = lane >> 4, l15 = lane & 15;

    if (t < 16) *(float4*)&b1S[4 * t] = ((const float4*)b1)[t];

    // ---- stage X, split to bf16 hi/lo; rows 62,63 zeroed ----
    const float4* xg4 = (const float4*)(x + (size_t)g * NN * FIN);
    for (int e = t; e < 2048; e += 256) {
        int row = e >> 5, k4 = e & 31;
        float4 v = {0.f, 0.f, 0.f, 0.f};
        if (e < 1984) v = xg4[e];
        us4 hh, ll;
        hh[0] = f2bf(v.x); ll[0] = f2bf(v.x - bf2f(hh[0]));
        hh[1] = f2bf(v.y); ll[1] = f2bf(v.y - bf2f(hh[1]));
        hh[2] = f2bf(v.z); ll[2] = f2bf(v.z - bf2f(hh[2]));
        hh[3] = f2bf(v.w); ll[3] = f2bf(v.w - bf2f(hh[3]));
        *(us4*)&SH[       row * 136 + k4 * 4] = hh;
        *(us4*)&SH[8704 + row * 136 + k4 * 4] = ll;
    }
    // ---- stage W hi/lo (contiguous 2176 f4 from ws) ----
    {
        const float4* wsrc = (const float4*)(wsu + 9216);
        for (int e = t; e < 2176; e += 256) *(float4*)&SH[17408 + e * 8] = wsrc[e];
    }
    __syncthreads();

    // ---- P1: wave wv -> Y rows 16wv+l15 ; 4 col-tiles ----
    f32x4 y0 = {0,0,0,0}, y1 = {0,0,0,0}, y2 = {0,0,0,0}, y3 = {0,0,0,0};
    {
        const int arow = (16 * wv + l15) * 136 + quad * 8;
#pragma unroll
        for (int c = 0; c < 4; ++c) {
            bf16x8 ahi = *(bf16x8*)&SH[arow + c * 32];
            bf16x8 alo = *(bf16x8*)&SH[8704 + arow + c * 32];
#define P1TILE(ACC, NT) { \
            int bo = (16 * NT + l15) * 136 + quad * 8 + c * 32; \
            bf16x8 bhi = *(bf16x8*)&SH[17408 + bo]; \
            bf16x8 blo = *(bf16x8*)&SH[26112 + bo]; \
            ACC = __builtin_amdgcn_mfma_f32_16x16x32_bf16(ahi, bhi, ACC, 0, 0, 0); \
            ACC = __builtin_amdgcn_mfma_f32_16x16x32_bf16(ahi, blo, ACC, 0, 0, 0); \
            ACC = __builtin_amdgcn_mfma_f32_16x16x32_bf16(alo, bhi, ACC, 0, 0, 0); \
            ACC = __builtin_amdgcn_mfma_f32_16x16x32_bf16(alo, blo, ACC, 0, 0, 0); }
            P1TILE(y0, 0) P1TILE(y1, 1) P1TILE(y2, 2) P1TILE(y3, 3)
#undef P1TILE
        }
    }
    __syncthreads();   // all phase-1 LDS reads done

    // ---- write Y transposed as bf16 hi/lo: YT[n=h][m], b64-packed over 4 regs ----
    {
        const int mbase = 16 * wv + quad * 4;
#define YTW(ACC, NT) { \
        int n = 16 * NT + l15; \
        us4 hh, ll; \
        hh[0] = f2bf(ACC[0]); ll[0] = f2bf(ACC[0] - bf2f(hh[0])); \
        hh[1] = f2bf(ACC[1]); ll[1] = f2bf(ACC[1] - bf2f(hh[1])); \
        hh[2] = f2bf(ACC[2]); ll[2] = f2bf(ACC[2] - bf2f(hh[2])); \
        hh[3] = f2bf(ACC[3]); ll[3] = f2bf(ACC[3] - bf2f(hh[3])); \
        *(us4*)&SH[       n * 72 + mbase] = hh; \
        *(us4*)&SH[4608 + n * 72 + mbase] = ll; }
        YTW(y0, 0) YTW(y1, 1) YTW(y2, 2) YTW(y3, 3)
#undef YTW
    }
    // ---- stage A2 hi/lo (contiguous 1152 f4 from ws) into SH[9216..18432) ----
    {
        const float4* a2src = (const float4*)wsu;
        for (int e = t; e < 1152; e += 256) *(float4*)&SH[9216 + e * 8] = a2src[e];
    }
    __syncthreads();

    // ---- P2: Z = A2 @ Y ; wave wv -> Z rows 16wv+l15 ----
    f32x4 z0 = {0,0,0,0}, z1 = {0,0,0,0}, z2 = {0,0,0,0}, z3 = {0,0,0,0};
    {
        const int arow = 9216 + (16 * wv + l15) * 72 + quad * 8;
#pragma unroll
        for (int c = 0; c < 2; ++c) {
            bf16x8 ahi = *(bf16x8*)&SH[arow + c * 32];
            bf16x8 alo = *(bf16x8*)&SH[4608 + arow + c * 32];
#define P2TILE(ACC, NT) { \
            int bo = (16 * NT + l15) * 72 + quad * 8 + c * 32; \
            bf16x8 bhi = *(bf16x8*)&SH[bo]; \
            bf16x8 blo = *(bf16x8*)&SH[4608 + bo]; \
            ACC = __builtin_amdgcn_mfma_f32_16x16x32_bf16(ahi, bhi, ACC, 0, 0, 0); \
            ACC = __builtin_amdgcn_mfma_f32_16x16x32_bf16(ahi, blo, ACC, 0, 0, 0); \
            ACC = __builtin_amdgcn_mfma_f32_16x16x32_bf16(alo, bhi, ACC, 0, 0, 0); \
            ACC = __builtin_amdgcn_mfma_f32_16x16x32_bf16(alo, blo, ACC, 0, 0, 0); }
            P2TILE(z0, 0) P2TILE(z1, 1) P2TILE(z2, 2) P2TILE(z3, 3)
#undef P2TILE
        }
    }

    // ---- epilogue: +b1, relu, mask pad rows, partial pool ----
    {
        const int mbase = 16 * wv + quad * 4;
        const int slot = 4 * wv + quad;
#define POOL(ACC, NT) { \
        int n = 16 * NT + l15; \
        float bn = b1S[n]; \
        float p = 0.f; \
        if (mbase + 0 < 62) p += fmaxf(ACC[0] + bn, 0.f); \
        if (mbase + 1 < 62) p += fmaxf(ACC[1] + bn, 0.f); \
        if (mbase + 2 < 62) p += fmaxf(ACC[2] + bn, 0.f); \
        if (mbase + 3 < 62) p += fmaxf(ACC[3] + bn, 0.f); \
        partial[n * 17 + slot] = p; }
        POOL(z0, 0) POOL(z1, 1) POOL(z2, 2) POOL(z3, 3)
#undef POOL
    }
    __syncthreads();

    if (t < HD) {
        float s = 0.f;
        for (int q = 0; q < 16; ++q) s += partial[t * 17 + q];
        out[(size_t)g * HD + t] = s;
        pooledS[t] = s;
    }
    __syncthreads();

    if (t < NC) {
        float lg[NC];
#pragma unroll
        for (int c = 0; c < NC; ++c) {
            float zz = b2[c];
            for (int h = 0; h < HD; ++h) zz += pooledS[h] * W2[c * HD + h];
            lg[c] = zz;
        }
        float m = fmaxf(lg[0], fmaxf(lg[1], lg[2]));
        float lse = m + logf(expf(lg[0] - m) + expf(lg[1] - m) + expf(lg[2] - m));
        out[(size_t)BGR * HD + (size_t)g * NC + t] = lg[t] - lse;
    }
}

extern "C" void kernel_launch(void* const* d_in, const int* in_sizes, int n_in,
                              void* d_out, int out_size, void* d_ws, size_t ws_size,
                              hipStream_t stream) {
    const float* x    = (const float*)d_in[0];
    const float* tril = (const float*)d_in[1];
    const float* W1   = (const float*)d_in[2];
    const float* b1   = (const float*)d_in[3];
    const float* W2   = (const float*)d_in[4];
    const float* b2   = (const float*)d_in[5];
    float* out = (float*)d_out;
    unsigned short* wsu = (unsigned short*)d_ws;

    prep_kernel<<<5, 256, 0, stream>>>(tril, W1, wsu);
    gcn_fused<<<BGR, 256, 0, stream>>>(x, wsu, b1, W2, b2, out);
}

// Round 5
// 102.281 us; speedup vs baseline: 1.2045x; 1.0211x over previous
//
#include <hip/hip_runtime.h>
#include <math.h>

#define NN  62
#define BGR 512
#define FIN 128
#define HD  64
#define NC  3

typedef __attribute__((ext_vector_type(8))) short          bf16x8;
typedef __attribute__((ext_vector_type(4))) float          f32x4;
typedef __attribute__((ext_vector_type(4))) unsigned short us4;

static __device__ __forceinline__ unsigned short f2bf(float f) {
    union { float f; unsigned u; } v; v.f = f;
    unsigned u = v.u;
    return (unsigned short)((u + 0x7fffu + ((u >> 16) & 1u)) >> 16);   // RNE
}
static __device__ __forceinline__ float bf2f(unsigned short h) {
    union { unsigned u; float f; } v; v.u = ((unsigned)h) << 16;
    return v.f;
}

// Single fused kernel. LDS map (ushort offsets in SH):
//  phase 1a: XHI 0..8704 (64x136), XLO 8704..17408
//            AcHI 17408..22016 (64 rows x 72), AcLO 22016..26624
//  phase 1b: WHI 17408..26112 (64x136), WLO 26112..34816   (overwrites Ac after A^2)
//  phase 2 : YTHI 0..4608 (64x72), YTLO 4608..9216, A2HI 9216..13824, A2LO 13824..18432
// All overlaps separated by barriers. A held as split-bf16; A^2 = (Ahi+Alo)@(Ahi+Alo)
// via 4-term MFMA (A symmetric => row-major LDS reads serve A- and B-frags; A^2
// symmetric => the transposed C-layout store equals the row-major home).
__global__ __launch_bounds__(256) void gcn_all(
    const float* __restrict__ x, const float* __restrict__ tril,
    const float* __restrict__ W1, const float* __restrict__ b1,
    const float* __restrict__ W2, const float* __restrict__ b2,
    float* __restrict__ out) {
    __shared__ unsigned short SH[34816];          // 68 KB
    __shared__ float TAIL[1088 + 64 + 64];        // partial(64x17), b1S(64), dinv(64)
    float* partial = TAIL;
    float* b1S     = TAIL + 1088;
    float* dinvS   = TAIL + 1152;

    const int t = threadIdx.x;
    const int g = blockIdx.x;
    const int lane = t & 63, wv = t >> 6, quad = lane >> 4, l15 = lane & 15;

    if (t < 16) *(float4*)&b1S[4 * t] = ((const float4*)b1)[t];

    // ---- stage X split; rows 62,63 zeroed ----
    const float4* xg4 = (const float4*)(x + (size_t)g * NN * FIN);
    for (int e = t; e < 2048; e += 256) {
        int row = e >> 5, k4 = e & 31;
        float4 v = {0.f, 0.f, 0.f, 0.f};
        if (e < 1984) v = xg4[e];
        us4 hh, ll;
        hh[0] = f2bf(v.x); ll[0] = f2bf(v.x - bf2f(hh[0]));
        hh[1] = f2bf(v.y); ll[1] = f2bf(v.y - bf2f(hh[1]));
        hh[2] = f2bf(v.z); ll[2] = f2bf(v.z - bf2f(hh[2]));
        hh[3] = f2bf(v.w); ll[3] = f2bf(v.w - bf2f(hh[3]));
        *(us4*)&SH[       row * 136 + k4 * 4] = hh;
        *(us4*)&SH[8704 + row * 136 + k4 * 4] = ll;
    }
    // ---- dinv (wave 0; tril is 7.8 KB, L1/L2-hot) ----
    if (t < 64) {
        float s = 0.f;
        if (t < NN) {
            for (int j = 0; j < NN; ++j) {
                int hi = max(t, j), lo = min(t, j);
                s += fabsf(tril[hi * (hi + 1) / 2 + lo]);
            }
            s = (s > 0.f) ? (1.0f / sqrtf(s)) : 0.f;
        }
        dinvS[t] = s;     // 0 for rows 62,63
    }
    __syncthreads();

    // ---- build A = D^-1/2 W D^-1/2 as split-bf16 into Ac (rows 62,63 / cols >=62 zero) ----
    for (int e4 = t; e4 < 1024; e4 += 256) {
        int i = e4 >> 4, j0 = (e4 & 15) * 4;
        float di = dinvS[i];
        float4 dj4 = *(float4*)&dinvS[j0];
        float dja[4] = {dj4.x, dj4.y, dj4.z, dj4.w};
        us4 hh, ll;
#pragma unroll
        for (int r = 0; r < 4; ++r) {
            int j = j0 + r;
            float w = 0.f;
            if (i < NN && j < NN) {
                int hi = max(i, j), lo = min(i, j);
                w = tril[hi * (hi + 1) / 2 + lo];
            }
            float v = di * w * dja[r];
            hh[r] = f2bf(v);
            ll[r] = f2bf(v - bf2f(hh[r]));
        }
        *(us4*)&SH[17408 + i * 72 + j0] = hh;
        *(us4*)&SH[22016 + i * 72 + j0] = ll;
    }
    __syncthreads();

    // ---- A^2 = A @ A via MFMA (P2-pattern), result kept in regs ----
    f32x4 za0 = {0,0,0,0}, za1 = {0,0,0,0}, za2 = {0,0,0,0}, za3 = {0,0,0,0};
    {
        const int arow = 17408 + (16 * wv + l15) * 72 + quad * 8;
#pragma unroll
        for (int c = 0; c < 2; ++c) {
            bf16x8 ahi = *(bf16x8*)&SH[arow + c * 32];
            bf16x8 alo = *(bf16x8*)&SH[4608 + arow + c * 32];
#define ATILE(ACC, NT) { \
            int bo = 17408 + (16 * NT + l15) * 72 + quad * 8 + c * 32; \
            bf16x8 bhi = *(bf16x8*)&SH[bo]; \
            bf16x8 blo = *(bf16x8*)&SH[4608 + bo]; \
            ACC = __builtin_amdgcn_mfma_f32_16x16x32_bf16(ahi, bhi, ACC, 0, 0, 0); \
            ACC = __builtin_amdgcn_mfma_f32_16x16x32_bf16(ahi, blo, ACC, 0, 0, 0); \
            ACC = __builtin_amdgcn_mfma_f32_16x16x32_bf16(alo, bhi, ACC, 0, 0, 0); \
            ACC = __builtin_amdgcn_mfma_f32_16x16x32_bf16(alo, blo, ACC, 0, 0, 0); }
            ATILE(za0, 0) ATILE(za1, 1) ATILE(za2, 2) ATILE(za3, 3)
#undef ATILE
        }
    }
    __syncthreads();   // Ac reads done -> W may overwrite

    // ---- stage W1 split from global (coalesced) ----
    {
        const float4* w14 = (const float4*)W1;
        for (int e = t; e < 2048; e += 256) {
            int h = e >> 5, f4 = e & 31;
            float4 v = w14[e];
            us4 hh, ll;
            hh[0] = f2bf(v.x); ll[0] = f2bf(v.x - bf2f(hh[0]));
            hh[1] = f2bf(v.y); ll[1] = f2bf(v.y - bf2f(hh[1]));
            hh[2] = f2bf(v.z); ll[2] = f2bf(v.z - bf2f(hh[2]));
            hh[3] = f2bf(v.w); ll[3] = f2bf(v.w - bf2f(hh[3]));
            *(us4*)&SH[17408 + h * 136 + f4 * 4] = hh;
            *(us4*)&SH[26112 + h * 136 + f4 * 4] = ll;
        }
    }
    __syncthreads();

    // ---- P1: Y = X @ W1^T ----
    f32x4 y0 = {0,0,0,0}, y1 = {0,0,0,0}, y2 = {0,0,0,0}, y3 = {0,0,0,0};
    {
        const int arow = (16 * wv + l15) * 136 + quad * 8;
#pragma unroll
        for (int c = 0; c < 4; ++c) {
            bf16x8 ahi = *(bf16x8*)&SH[arow + c * 32];
            bf16x8 alo = *(bf16x8*)&SH[8704 + arow + c * 32];
#define P1TILE(ACC, NT) { \
            int bo = (16 * NT + l15) * 136 + quad * 8 + c * 32; \
            bf16x8 bhi = *(bf16x8*)&SH[17408 + bo]; \
            bf16x8 blo = *(bf16x8*)&SH[26112 + bo]; \
            ACC = __builtin_amdgcn_mfma_f32_16x16x32_bf16(ahi, bhi, ACC, 0, 0, 0); \
            ACC = __builtin_amdgcn_mfma_f32_16x16x32_bf16(ahi, blo, ACC, 0, 0, 0); \
            ACC = __builtin_amdgcn_mfma_f32_16x16x32_bf16(alo, bhi, ACC, 0, 0, 0); \
            ACC = __builtin_amdgcn_mfma_f32_16x16x32_bf16(alo, blo, ACC, 0, 0, 0); }
            P1TILE(y0, 0) P1TILE(y1, 1) P1TILE(y2, 2) P1TILE(y3, 3)
#undef P1TILE
        }
    }
    __syncthreads();   // all phase-1 LDS reads done

    // ---- write YT (transposed) and A2 (symmetric -> transposed store == itself) ----
    {
        const int mbase = 16 * wv + quad * 4;
#define SPLITW(ACC, NT, HIOFF, LOOFF) { \
        int n = 16 * NT + l15; \
        us4 hh, ll; \
        hh[0] = f2bf(ACC[0]); ll[0] = f2bf(ACC[0] - bf2f(hh[0])); \
        hh[1] = f2bf(ACC[1]); ll[1] = f2bf(ACC[1] - bf2f(hh[1])); \
        hh[2] = f2bf(ACC[2]); ll[2] = f2bf(ACC[2] - bf2f(hh[2])); \
        hh[3] = f2bf(ACC[3]); ll[3] = f2bf(ACC[3] - bf2f(hh[3])); \
        *(us4*)&SH[(HIOFF) + n * 72 + mbase] = hh; \
        *(us4*)&SH[(LOOFF) + n * 72 + mbase] = ll; }
        SPLITW(y0, 0, 0, 4608) SPLITW(y1, 1, 0, 4608)
        SPLITW(y2, 2, 0, 4608) SPLITW(y3, 3, 0, 4608)
        SPLITW(za0, 0, 9216, 13824) SPLITW(za1, 1, 9216, 13824)
        SPLITW(za2, 2, 9216, 13824) SPLITW(za3, 3, 9216, 13824)
#undef SPLITW
    }
    __syncthreads();

    // ---- P2: Z = A2 @ Y ----
    f32x4 z0 = {0,0,0,0}, z1 = {0,0,0,0}, z2 = {0,0,0,0}, z3 = {0,0,0,0};
    {
        const int arow = 9216 + (16 * wv + l15) * 72 + quad * 8;
#pragma unroll
        for (int c = 0; c < 2; ++c) {
            bf16x8 ahi = *(bf16x8*)&SH[arow + c * 32];
            bf16x8 alo = *(bf16x8*)&SH[4608 + arow + c * 32];
#define P2TILE(ACC, NT) { \
            int bo = (16 * NT + l15) * 72 + quad * 8 + c * 32; \
            bf16x8 bhi = *(bf16x8*)&SH[bo]; \
            bf16x8 blo = *(bf16x8*)&SH[4608 + bo]; \
            ACC = __builtin_amdgcn_mfma_f32_16x16x32_bf16(ahi, bhi, ACC, 0, 0, 0); \
            ACC = __builtin_amdgcn_mfma_f32_16x16x32_bf16(ahi, blo, ACC, 0, 0, 0); \
            ACC = __builtin_amdgcn_mfma_f32_16x16x32_bf16(alo, bhi, ACC, 0, 0, 0); \
            ACC = __builtin_amdgcn_mfma_f32_16x16x32_bf16(alo, blo, ACC, 0, 0, 0); }
            P2TILE(z0, 0) P2TILE(z1, 1) P2TILE(z2, 2) P2TILE(z3, 3)
#undef P2TILE
        }
    }

    // ---- epilogue: +b1, relu, mask pad rows, partial pool ----
    {
        const int mbase = 16 * wv + quad * 4;
        const int slot = 4 * wv + quad;
#define POOL(ACC, NT) { \
        int n = 16 * NT + l15; \
        float bn = b1S[n]; \
        float p = 0.f; \
        if (mbase + 0 < 62) p += fmaxf(ACC[0] + bn, 0.f); \
        if (mbase + 1 < 62) p += fmaxf(ACC[1] + bn, 0.f); \
        if (mbase + 2 < 62) p += fmaxf(ACC[2] + bn, 0.f); \
        if (mbase + 3 < 62) p += fmaxf(ACC[3] + bn, 0.f); \
        partial[n * 17 + slot] = p; }
        POOL(z0, 0) POOL(z1, 1) POOL(z2, 2) POOL(z3, 3)
#undef POOL
    }
    __syncthreads();

    // ---- wave-0 tail: pool-reduce, latent write, logits via shuffle, log_softmax ----
    if (t < HD) {
        float s = 0.f;
#pragma unroll
        for (int q = 0; q < 16; ++q) s += partial[t * 17 + q];
        out[(size_t)g * HD + t] = s;
        float l0 = s * W2[t];                 // W2 rows: [c][h], 768 B, L2-hot
        float l1 = s * W2[64 + t];
        float l2 = s * W2[128 + t];
#pragma unroll
        for (int off = 32; off > 0; off >>= 1) {
            l0 += __shfl_down(l0, off);
            l1 += __shfl_down(l1, off);
            l2 += __shfl_down(l2, off);
        }
        if (t == 0) {
            l0 += b2[0]; l1 += b2[1]; l2 += b2[2];
            float m = fmaxf(l0, fmaxf(l1, l2));
            float lse = m + logf(expf(l0 - m) + expf(l1 - m) + expf(l2 - m));
            float* lp = out + (size_t)BGR * HD + (size_t)g * NC;
            lp[0] = l0 - lse; lp[1] = l1 - lse; lp[2] = l2 - lse;
        }
    }
}

extern "C" void kernel_launch(void* const* d_in, const int* in_sizes, int n_in,
                              void* d_out, int out_size, void* d_ws, size_t ws_size,
                              hipStream_t stream) {
    const float* x    = (const float*)d_in[0];
    const float* tril = (const float*)d_in[1];
    const float* W1   = (const float*)d_in[2];
    const float* b1   = (const float*)d_in[3];
    const float* W2   = (const float*)d_in[4];
    const float* b2   = (const float*)d_in[5];
    float* out = (float*)d_out;

    gcn_all<<<BGR, 256, 0, stream>>>(x, tril, W1, b1, W2, b2, out);
}